// Round 6
// baseline (363.894 us; speedup 1.0000x reference)
//
#include <hip/hip_runtime.h>

typedef __bf16 bf16x8 __attribute__((ext_vector_type(8)));
typedef __bf16 bf16x4 __attribute__((ext_vector_type(4)));
typedef __bf16 bf16x2 __attribute__((ext_vector_type(2)));
typedef float  floatx4 __attribute__((ext_vector_type(4)));

#define MFMA16(a,b,c) __builtin_amdgcn_mfma_f32_16x16x32_bf16(a,b,c,0,0,0)

constexpr int DIM  = 512;
constexpr int SEQ  = 4096;
constexpr int HD   = 64;
// 0.125 (HEAD_DIM^-0.5) * log2(e), folded into Q so softmax uses exp2 directly
constexpr float QSCALE = 0.1803368801111244f;

static __device__ inline __bf16 f2bf(float f) {
    unsigned int u = __builtin_bit_cast(unsigned int, f);
    u += 0x7fffu + ((u >> 16) & 1u);
    return __builtin_bit_cast(__bf16, (unsigned short)(u >> 16));
}
#if __has_builtin(__builtin_amdgcn_cvt_pk_bf16_f32)
static __device__ inline bf16x2 pk2(float a, float b) {
    return __builtin_amdgcn_cvt_pk_bf16_f32(a, b);
}
#else
static __device__ inline bf16x2 pk2(float a, float b) {
    bf16x2 r; r[0] = f2bf(a); r[1] = f2bf(b); return r;
}
#endif
#if __has_builtin(__builtin_amdgcn_exp2f)
#define EXP2(x) __builtin_amdgcn_exp2f(x)
#else
#define EXP2(x) exp2f(x)
#endif
static __device__ inline bf16x8 cvt8(floatx4 lo, floatx4 hi) {
    bf16x2 p0 = pk2(lo[0], lo[1]), p1 = pk2(lo[2], lo[3]);
    bf16x2 p2 = pk2(hi[0], hi[1]), p3 = pk2(hi[2], hi[3]);
    bf16x8 r;
    r[0]=p0[0]; r[1]=p0[1]; r[2]=p1[0]; r[3]=p1[1];
    r[4]=p2[0]; r[5]=p2[1]; r[6]=p3[0]; r[7]=p3[1];
    return r;
}

// Blocked fragment layout for Q and K (A/B-operand ready, b128 loads):
//   blk[bh][s>>4][d>>5][lane][8], lane = ((d>>3)&3)*16 + (s&15), slot = d&7
// V blocked under key-permutation pi(q,j)=16*(j>=4)+4q+(j&3):
//   Vblk[bh][s>>5][d>>4][lane][8], lane = ((s>>2)&3)*16 + (d&15),
//   slot j = (s&3) + ((s>>4)&1)*4.

// ---------------------------------------------------------------------------
// Stage 1: qkv = x @ w_qkv^T + b_qkv (fp32 in, bf16 MFMA, blocked bf16 out).
// Q/K n-blocks compute C^T (swapped MFMA operands, same fragment loads) so
// the blocked layout is written with bf16x4 stores; V uses normal orientation.
// ---------------------------------------------------------------------------
__global__ __launch_bounds__(256)
void gemm_qkv(const float* __restrict__ X, const float* __restrict__ W,
              const float* __restrict__ bias,
              __bf16* __restrict__ Qb, __bf16* __restrict__ Kb, __bf16* __restrict__ Vb)
{
    __shared__ __bf16 As[128*32];
    __shared__ __bf16 Bs[128*32];
    const int tid  = threadIdx.x;
    const int lane = tid & 63;
    const int wave = tid >> 6;
    const int quad = lane >> 4;
    const int l16  = lane & 15;
    const int waveM = wave >> 1, waveN = wave & 1;
    const int mBase = blockIdx.y * 128;
    const int nBase = blockIdx.x * 128;
    const int which = nBase >> 9;          // 0=q 1=k 2=v (uniform per block)

    floatx4 zero = {0.f, 0.f, 0.f, 0.f};
    floatx4 acc[4][4];
    for (int i = 0; i < 4; i++)
        for (int j = 0; j < 4; j++) acc[i][j] = zero;

    const int srow = tid >> 2;        // 0..63
    const int scol = (tid & 3) * 8;   // 0,8,16,24

    for (int k0 = 0; k0 < DIM; k0 += 32) {
        const float* xr0 = X + (size_t)(mBase + srow)      * DIM + k0 + scol;
        const float* xr1 = X + (size_t)(mBase + 64 + srow) * DIM + k0 + scol;
        const float* wr0 = W + (size_t)(nBase + srow)      * DIM + k0 + scol;
        const float* wr1 = W + (size_t)(nBase + 64 + srow) * DIM + k0 + scol;
        bf16x8 a0 = cvt8(*(const floatx4*)xr0, *(const floatx4*)(xr0 + 4));
        bf16x8 a1 = cvt8(*(const floatx4*)xr1, *(const floatx4*)(xr1 + 4));
        bf16x8 b0 = cvt8(*(const floatx4*)wr0, *(const floatx4*)(wr0 + 4));
        bf16x8 b1 = cvt8(*(const floatx4*)wr1, *(const floatx4*)(wr1 + 4));
        *(bf16x8*)&As[srow*32 + scol]      = a0;
        *(bf16x8*)&As[(64+srow)*32 + scol] = a1;
        *(bf16x8*)&Bs[srow*32 + scol]      = b0;
        *(bf16x8*)&Bs[(64+srow)*32 + scol] = b1;
        __syncthreads();
        bf16x8 af[4], bfr[4];
        for (int mi = 0; mi < 4; mi++)
            af[mi]  = *(const bf16x8*)&As[(waveM*64 + mi*16 + l16)*32 + quad*8];
        for (int ni = 0; ni < 4; ni++)
            bfr[ni] = *(const bf16x8*)&Bs[(waveN*64 + ni*16 + l16)*32 + quad*8];
        if (which == 2) {
            for (int mi = 0; mi < 4; mi++)
                for (int ni = 0; ni < 4; ni++)
                    acc[mi][ni] = MFMA16(af[mi], bfr[ni], acc[mi][ni]);
        } else {
            // transposed: rows = W-rows (d), cols = X-rows (s)
            for (int mi = 0; mi < 4; mi++)
                for (int ni = 0; ni < 4; ni++)
                    acc[mi][ni] = MFMA16(bfr[ni], af[mi], acc[mi][ni]);
        }
        __syncthreads();
    }

    if (which == 2) {
        // V epilogue (normal orientation): rows = s, cols = n/d
        for (int ni = 0; ni < 4; ni++) {
            const int n = nBase + waveN*64 + ni*16 + l16;
            const float bv = bias[n];
            const int h = (n >> 6) & 7;
            const int d = n & 63;
            for (int mi = 0; mi < 4; mi++) {
                const int m0 = mBase + waveM*64 + mi*16 + quad*4;
                const int b  = m0 >> 12;
                const int s0 = m0 & 4095;
                const int bh = (b << 3) | h;
                bf16x4 v;
                for (int r = 0; r < 4; r++) v[r] = f2bf(acc[mi][ni][r] + bv);
                size_t off = (((((size_t)bh*128 + (s0 >> 5))*4 + (d >> 4))*64)
                              + ((s0 >> 2) & 3)*16 + (d & 15))*8 + ((s0 >> 4) & 1)*4;
                *(bf16x4*)&Vb[off] = v;
            }
        }
    } else {
        // Q/K epilogue (transposed): rows = d (quad*4+r), cols = s (l16)
        __bf16* dst = (which == 0) ? Qb : Kb;
        for (int ni = 0; ni < 4; ni++) {
            const int n0 = nBase + waveN*64 + ni*16 + quad*4;
            const floatx4 b4 = *(const floatx4*)&bias[n0];
            const int dfull = n0 & 511;           // 0..511 within q or k section
            const int h  = dfull >> 6;
            const int d0 = dfull & 63;            // 4-aligned
            const int lgrp = ((d0 >> 3) & 3)*16 + l16;
            const int half = d0 >> 5;
            const int slot = d0 & 7;              // 0 or 4
            for (int mi = 0; mi < 4; mi++) {
                const int m = mBase + waveM*64 + mi*16 + l16;
                const int b = m >> 12, s = m & 4095;
                const int bh = (b << 3) | h;
                bf16x4 v;
                for (int r = 0; r < 4; r++) {
                    float val = acc[mi][ni][r] + b4[r];
                    if (which == 0) val *= QSCALE;
                    v[r] = f2bf(val);
                }
                size_t off = ((((size_t)bh*256 + (s >> 4))*2 + half)*64 + lgrp)*8 + slot;
                *(bf16x4*)&dst[off] = v;
            }
        }
    }
}

// ---------------------------------------------------------------------------
// Stage 2: flash attention — zero LDS in main loop, all Q/K/V fragment loads
// coalesced b128 from blocked workspace, register double-buffered prefetch,
// L accumulated via ones-MFMA (C layout, no shuffles). S^T = K Q^T; exp2
// packed in-register is the PV B-operand under pi; O^T in C layout.
// Wave w handles all 64 q x keys [1024w,1024w+1024). Combine via small LDS.
// ---------------------------------------------------------------------------
__global__ __launch_bounds__(256, 3)
void attn_kernel(const __bf16* __restrict__ Qb, const __bf16* __restrict__ Kb,
                 const __bf16* __restrict__ Vb, __bf16* __restrict__ Ao)
{
    __shared__ __bf16 Ob[3][64*68];   // bf16 partial O^T, stride 68
    __shared__ float  Lb[4][64];
    const int tid  = threadIdx.x;
    const int lane = tid & 63;
    const int wave = tid >> 6;
    const int quad = lane >> 4;
    const int l16  = lane & 15;
    const int bh    = blockIdx.x;         // 0..15
    const int qBase = blockIdx.y * 64;

    const __bf16* qg = Qb + (size_t)bh*256*2*512;
    const __bf16* kg = Kb + (size_t)bh*256*2*512;
    const __bf16* vg = Vb + (size_t)bh*128*4*512;

    // Q as B-operand from blocked layout: one b128 per (t,hb)
    bf16x8 qf[4][2];
    for (int t = 0; t < 4; t++)
        for (int hb = 0; hb < 2; hb++)
            qf[t][hb] = *(const bf16x8*)(qg
                + ((size_t)((qBase >> 4) + t)*2 + hb)*512 + lane*8);

    floatx4 zero = {0.f, 0.f, 0.f, 0.f};
    floatx4 oacc[4][4];   // [t][od]: O^T tile, row d=od*16+quad*4+r, col q=t*16+l16
    for (int t = 0; t < 4; t++)
        for (int od = 0; od < 4; od++) oacc[t][od] = zero;
    floatx4 Lt[4];        // ones-MFMA accumulators: all rows = L[q]
    for (int t = 0; t < 4; t++) Lt[t] = zero;

    bf16x8 ones;
    for (int j = 0; j < 8; j++) ones[j] = f2bf(1.0f);

    const int key_begin = wave * 1024;

    bf16x8 kbA[2][2], vbA[4], kbB[2][2], vbB[4];

    auto load = [&](int key0, bf16x8 (&kb)[2][2], bf16x8 (&vb)[4]) {
        const __bf16* kbase = kg + (size_t)(key0 >> 4)*1024 + lane*8;
        for (int kt = 0; kt < 2; kt++)
            for (int hb = 0; hb < 2; hb++)
                kb[kt][hb] = *(const bf16x8*)(kbase + ((size_t)kt*2 + hb)*512);
        const __bf16* vbase = vg + (size_t)(key0 >> 5)*2048 + lane*8;
        for (int od = 0; od < 4; od++)
            vb[od] = *(const bf16x8*)(vbase + (size_t)od*512);
    };

    auto proc = [&](const bf16x8 (&kb)[2][2], const bf16x8 (&vb)[4]) {
        for (int t = 0; t < 4; t++) {
            floatx4 z0 = zero, z1 = zero;
            z0 = MFMA16(kb[0][0], qf[t][0], z0);
            z0 = MFMA16(kb[0][1], qf[t][1], z0);
            z1 = MFMA16(kb[1][0], qf[t][0], z1);
            z1 = MFMA16(kb[1][1], qf[t][1], z1);
            float e0[4], e1[4];
            for (int r = 0; r < 4; r++) { e0[r] = EXP2(z0[r]); e1[r] = EXP2(z1[r]); }
            bf16x2 p0 = pk2(e0[0], e0[1]), p1 = pk2(e0[2], e0[3]);
            bf16x2 p2 = pk2(e1[0], e1[1]), p3 = pk2(e1[2], e1[3]);
            bf16x8 pb;
            pb[0]=p0[0]; pb[1]=p0[1]; pb[2]=p1[0]; pb[3]=p1[1];
            pb[4]=p2[0]; pb[5]=p2[1]; pb[6]=p3[0]; pb[7]=p3[1];
            Lt[t] = MFMA16(ones, pb, Lt[t]);
            for (int od = 0; od < 4; od++)
                oacc[t][od] = MFMA16(vb[od], pb, oacc[t][od]);
        }
    };

    load(key_begin, kbA, vbA);
    for (int i = 0; i < 32; i += 2) {
        load(key_begin + ((i + 1) & 31)*32, kbB, vbB);
        proc(kbA, vbA);
        load(key_begin + ((i + 2) & 31)*32, kbA, vbA);
        proc(kbB, vbB);
    }

    // L[q] replicated across all rows/quads of Lt[t]
    if (lane < 16)
        for (int t = 0; t < 4; t++) Lb[wave][t*16 + lane] = Lt[t][0];
    __syncthreads();
    float inv[4];
    for (int t = 0; t < 4; t++) {
        const int q = t*16 + l16;
        inv[t] = 1.0f / (Lb[0][q] + Lb[1][q] + Lb[2][q] + Lb[3][q]);
    }
    if (wave != 0) {
        for (int t = 0; t < 4; t++)
            for (int od = 0; od < 4; od++) {
                bf16x4 v;
                for (int r = 0; r < 4; r++) v[r] = f2bf(oacc[t][od][r] * inv[t]);
                *(bf16x4*)&Ob[wave-1][(t*16 + l16)*68 + od*16 + quad*4] = v;
            }
    }
    __syncthreads();
    if (wave == 0) {
        const int b = bh >> 3, h = bh & 7;
        for (int t = 0; t < 4; t++) {
            const int s = qBase + t*16 + l16;
            for (int od = 0; od < 4; od++) {
                bf16x4 o0 = *(const bf16x4*)&Ob[0][(t*16 + l16)*68 + od*16 + quad*4];
                bf16x4 o1 = *(const bf16x4*)&Ob[1][(t*16 + l16)*68 + od*16 + quad*4];
                bf16x4 o2 = *(const bf16x4*)&Ob[2][(t*16 + l16)*68 + od*16 + quad*4];
                bf16x4 v;
                for (int r = 0; r < 4; r++) {
                    float o = oacc[t][od][r] * inv[t] +
                              (float)o0[r] + (float)o1[r] + (float)o2[r];
                    v[r] = f2bf(o);
                }
                *(bf16x4*)&Ao[((size_t)(b*SEQ + s))*DIM + h*HD + od*16 + quad*4] = v;
            }
        }
    }
}

// ---------------------------------------------------------------------------
// Stage 3: out = attn_out @ w_proj^T + b_proj  (bf16 A, fp32 W in, fp32 out)
// ---------------------------------------------------------------------------
__global__ __launch_bounds__(256)
void gemm_proj(const __bf16* __restrict__ A, const float* __restrict__ W,
               const float* __restrict__ bias, float* __restrict__ Out)
{
    __shared__ __bf16 As[128*32];
    __shared__ __bf16 Bs[128*32];
    const int tid  = threadIdx.x;
    const int lane = tid & 63;
    const int wave = tid >> 6;
    const int quad = lane >> 4;
    const int l16  = lane & 15;
    const int waveM = wave >> 1, waveN = wave & 1;
    const int mBase = blockIdx.y * 128;
    const int nBase = blockIdx.x * 128;

    floatx4 zero = {0.f, 0.f, 0.f, 0.f};
    floatx4 acc[4][4];
    for (int i = 0; i < 4; i++)
        for (int j = 0; j < 4; j++) acc[i][j] = zero;

    const int srow = tid >> 2;
    const int scol = (tid & 3) * 8;

    for (int k0 = 0; k0 < DIM; k0 += 32) {
        bf16x8 a0 = *(const bf16x8*)(A + (size_t)(mBase + srow)      * DIM + k0 + scol);
        bf16x8 a1 = *(const bf16x8*)(A + (size_t)(mBase + 64 + srow) * DIM + k0 + scol);
        const float* wr0 = W + (size_t)(nBase + srow)      * DIM + k0 + scol;
        const float* wr1 = W + (size_t)(nBase + 64 + srow) * DIM + k0 + scol;
        bf16x8 b0 = cvt8(*(const floatx4*)wr0, *(const floatx4*)(wr0 + 4));
        bf16x8 b1 = cvt8(*(const floatx4*)wr1, *(const floatx4*)(wr1 + 4));
        *(bf16x8*)&As[srow*32 + scol]      = a0;
        *(bf16x8*)&As[(64+srow)*32 + scol] = a1;
        *(bf16x8*)&Bs[srow*32 + scol]      = b0;
        *(bf16x8*)&Bs[(64+srow)*32 + scol] = b1;
        __syncthreads();
        bf16x8 af[4], bfr[4];
        for (int mi = 0; mi < 4; mi++)
            af[mi]  = *(const bf16x8*)&As[(waveM*64 + mi*16 + l16)*32 + quad*8];
        for (int ni = 0; ni < 4; ni++)
            bfr[ni] = *(const bf16x8*)&Bs[(waveN*64 + ni*16 + l16)*32 + quad*8];
        for (int mi = 0; mi < 4; mi++)
            for (int ni = 0; ni < 4; ni++)
                acc[mi][ni] = MFMA16(af[mi], bfr[ni], acc[mi][ni]);
        __syncthreads();
    }

    for (int ni = 0; ni < 4; ni++) {
        const int n = nBase + waveN*64 + ni*16 + l16;
        const float bv = bias[n];
        for (int mi = 0; mi < 4; mi++) {
            const int m0 = mBase + waveM*64 + mi*16 + quad*4;
            for (int r = 0; r < 4; r++) {
                const int mm = m0 + r;
                Out[(size_t)mm*DIM + n] = acc[mi][ni][r] + bv;
            }
        }
    }
}

extern "C" void kernel_launch(void* const* d_in, const int* in_sizes, int n_in,
                              void* d_out, int out_size, void* d_ws, size_t ws_size,
                              hipStream_t stream) {
    const float* x      = (const float*)d_in[0];   // [2,4096,512] fp32
    const float* w_qkv  = (const float*)d_in[1];   // [1536,512] fp32
    const float* b_qkv  = (const float*)d_in[2];   // [1536] fp32
    const float* w_proj = (const float*)d_in[3];   // [512,512] fp32
    const float* b_proj = (const float*)d_in[4];   // [512] fp32
    float* out = (float*)d_out;                    // [2,4096,512] fp32

    __bf16* ws  = (__bf16*)d_ws;
    const size_t PLANE = (size_t)16 * SEQ * HD;    // 4 Mi elements = 8 MB
    __bf16* Qbk = ws;                 // Qblk [16][256][2][64][8] (pre-scaled)
    __bf16* Kbk = ws + PLANE;         // Kblk [16][256][2][64][8]
    __bf16* Vbk = ws + 2*PLANE;       // Vblk [16][128][4][64][8]
    __bf16* Aob = ws + 3*PLANE;       // [2,4096,512] attention output (bf16)

    gemm_qkv<<<dim3(12, 64), 256, 0, stream>>>(x, w_qkv, b_qkv, Qbk, Kbk, Vbk);
    attn_kernel<<<dim3(16, 64), 256, 0, stream>>>(Qbk, Kbk, Vbk, Aob);
    gemm_proj<<<dim3(4, 64), 256, 0, stream>>>(Aob, w_proj, b_proj, out);
}

// Round 7
// 232.070 us; speedup vs baseline: 1.5680x; 1.5680x over previous
//
#include <hip/hip_runtime.h>

typedef __bf16 bf16x8 __attribute__((ext_vector_type(8)));
typedef __bf16 bf16x4 __attribute__((ext_vector_type(4)));
typedef __bf16 bf16x2 __attribute__((ext_vector_type(2)));
typedef float  floatx4 __attribute__((ext_vector_type(4)));
typedef unsigned int uint32;
typedef uint32 uintx4 __attribute__((ext_vector_type(4)));

#define MFMA16(a,b,c) __builtin_amdgcn_mfma_f32_16x16x32_bf16(a,b,c,0,0,0)

constexpr int DIM  = 512;
constexpr int SEQ  = 4096;
constexpr int HD   = 64;
// 0.125 (HEAD_DIM^-0.5) * log2(e), folded into Q so softmax uses exp2 directly
constexpr float QSCALE = 0.1803368801111244f;

static __device__ inline __bf16 f2bf(float f) {
    unsigned int u = __builtin_bit_cast(unsigned int, f);
    u += 0x7fffu + ((u >> 16) & 1u);
    return __builtin_bit_cast(__bf16, (unsigned short)(u >> 16));
}
#if __has_builtin(__builtin_amdgcn_cvt_pk_bf16_f32)
static __device__ inline bf16x2 pk2(float a, float b) {
    return __builtin_amdgcn_cvt_pk_bf16_f32(a, b);
}
#else
static __device__ inline bf16x2 pk2(float a, float b) {
    bf16x2 r; r[0] = f2bf(a); r[1] = f2bf(b); return r;
}
#endif
#if __has_builtin(__builtin_amdgcn_exp2f)
#define EXP2(x) __builtin_amdgcn_exp2f(x)
#else
#define EXP2(x) exp2f(x)
#endif
static __device__ inline bf16x8 cvt8(floatx4 lo, floatx4 hi) {
    uintx4 w;
    w[0] = __builtin_bit_cast(uint32, pk2(lo[0], lo[1]));
    w[1] = __builtin_bit_cast(uint32, pk2(lo[2], lo[3]));
    w[2] = __builtin_bit_cast(uint32, pk2(hi[0], hi[1]));
    w[3] = __builtin_bit_cast(uint32, pk2(hi[2], hi[3]));
    return __builtin_bit_cast(bf16x8, w);
}

// Blocked fragment layout for Q and K (A/B-operand ready, b128 loads):
//   blk[bh][s>>4][d>>5][lane][8], lane = ((d>>3)&3)*16 + (s&15), slot = d&7
// V blocked under key-permutation pi(q,j)=16*(j>=4)+4q+(j&3):
//   Vblk[bh][s>>5][d>>4][lane][8], lane = ((s>>2)&3)*16 + (d&15),
//   slot j = (s&3) + ((s>>4)&1)*4.

// ---------------------------------------------------------------------------
// Stage 1: qkv = x @ w_qkv^T + b_qkv (fp32 in, bf16 MFMA, blocked bf16 out).
// Q/K n-blocks compute C^T (swapped MFMA operands, same fragment loads) so
// the blocked layout is written with bf16x4 stores; V uses normal orientation.
// ---------------------------------------------------------------------------
__global__ __launch_bounds__(256)
void gemm_qkv(const float* __restrict__ X, const float* __restrict__ W,
              const float* __restrict__ bias,
              __bf16* __restrict__ Qb, __bf16* __restrict__ Kb, __bf16* __restrict__ Vb)
{
    __shared__ __bf16 As[128*32];
    __shared__ __bf16 Bs[128*32];
    const int tid  = threadIdx.x;
    const int lane = tid & 63;
    const int wave = tid >> 6;
    const int quad = lane >> 4;
    const int l16  = lane & 15;
    const int waveM = wave >> 1, waveN = wave & 1;
    const int mBase = blockIdx.y * 128;
    const int nBase = blockIdx.x * 128;
    const int which = nBase >> 9;          // 0=q 1=k 2=v (uniform per block)

    floatx4 zero = {0.f, 0.f, 0.f, 0.f};
    floatx4 acc[4][4];
    for (int i = 0; i < 4; i++)
        for (int j = 0; j < 4; j++) acc[i][j] = zero;

    const int srow = tid >> 2;        // 0..63
    const int scol = (tid & 3) * 8;   // 0,8,16,24

    for (int k0 = 0; k0 < DIM; k0 += 32) {
        const float* xr0 = X + (size_t)(mBase + srow)      * DIM + k0 + scol;
        const float* xr1 = X + (size_t)(mBase + 64 + srow) * DIM + k0 + scol;
        const float* wr0 = W + (size_t)(nBase + srow)      * DIM + k0 + scol;
        const float* wr1 = W + (size_t)(nBase + 64 + srow) * DIM + k0 + scol;
        bf16x8 a0 = cvt8(*(const floatx4*)xr0, *(const floatx4*)(xr0 + 4));
        bf16x8 a1 = cvt8(*(const floatx4*)xr1, *(const floatx4*)(xr1 + 4));
        bf16x8 b0 = cvt8(*(const floatx4*)wr0, *(const floatx4*)(wr0 + 4));
        bf16x8 b1 = cvt8(*(const floatx4*)wr1, *(const floatx4*)(wr1 + 4));
        *(bf16x8*)&As[srow*32 + scol]      = a0;
        *(bf16x8*)&As[(64+srow)*32 + scol] = a1;
        *(bf16x8*)&Bs[srow*32 + scol]      = b0;
        *(bf16x8*)&Bs[(64+srow)*32 + scol] = b1;
        __syncthreads();
        bf16x8 af[4], bfr[4];
        for (int mi = 0; mi < 4; mi++)
            af[mi]  = *(const bf16x8*)&As[(waveM*64 + mi*16 + l16)*32 + quad*8];
        for (int ni = 0; ni < 4; ni++)
            bfr[ni] = *(const bf16x8*)&Bs[(waveN*64 + ni*16 + l16)*32 + quad*8];
        if (which == 2) {
            for (int mi = 0; mi < 4; mi++)
                for (int ni = 0; ni < 4; ni++)
                    acc[mi][ni] = MFMA16(af[mi], bfr[ni], acc[mi][ni]);
        } else {
            // transposed: rows = W-rows (d), cols = X-rows (s)
            for (int mi = 0; mi < 4; mi++)
                for (int ni = 0; ni < 4; ni++)
                    acc[mi][ni] = MFMA16(bfr[ni], af[mi], acc[mi][ni]);
        }
        __syncthreads();
    }

    if (which == 2) {
        // V epilogue (normal orientation): rows = s, cols = n/d
        for (int ni = 0; ni < 4; ni++) {
            const int n = nBase + waveN*64 + ni*16 + l16;
            const float bv = bias[n];
            const int h = (n >> 6) & 7;
            const int d = n & 63;
            for (int mi = 0; mi < 4; mi++) {
                const int m0 = mBase + waveM*64 + mi*16 + quad*4;
                const int b  = m0 >> 12;
                const int s0 = m0 & 4095;
                const int bh = (b << 3) | h;
                bf16x4 v;
                for (int r = 0; r < 4; r++) v[r] = f2bf(acc[mi][ni][r] + bv);
                size_t off = (((((size_t)bh*128 + (s0 >> 5))*4 + (d >> 4))*64)
                              + ((s0 >> 2) & 3)*16 + (d & 15))*8 + ((s0 >> 4) & 1)*4;
                *(bf16x4*)&Vb[off] = v;
            }
        }
    } else {
        // Q/K epilogue (transposed): rows = d (quad*4+r), cols = s (l16)
        __bf16* dst = (which == 0) ? Qb : Kb;
        for (int ni = 0; ni < 4; ni++) {
            const int n0 = nBase + waveN*64 + ni*16 + quad*4;
            const floatx4 b4 = *(const floatx4*)&bias[n0];
            const int dfull = n0 & 511;           // 0..511 within q or k section
            const int h  = dfull >> 6;
            const int d0 = dfull & 63;            // 4-aligned
            const int lgrp = ((d0 >> 3) & 3)*16 + l16;
            const int half = d0 >> 5;
            const int slot = d0 & 7;              // 0 or 4
            for (int mi = 0; mi < 4; mi++) {
                const int m = mBase + waveM*64 + mi*16 + l16;
                const int b = m >> 12, s = m & 4095;
                const int bh = (b << 3) | h;
                bf16x4 v;
                for (int r = 0; r < 4; r++) {
                    float val = acc[mi][ni][r] + b4[r];
                    if (which == 0) val *= QSCALE;
                    v[r] = f2bf(val);
                }
                size_t off = ((((size_t)bh*256 + (s >> 4))*2 + half)*64 + lgrp)*8 + slot;
                *(bf16x4*)&dst[off] = v;
            }
        }
    }
}

// ---------------------------------------------------------------------------
// Stage 2: flash attention — R5 single-buffer loop (known 106 us), blocked
// coalesced b128 loads for Q/K/V, pointer-increment addressing, pb via
// bit_cast. S^T = K Q^T; exp2 packed in-register is the PV B-operand under
// pi; O^T in C layout. Wave w: all 64 q x keys [1024w,1024w+1024).
// ---------------------------------------------------------------------------
__global__ __launch_bounds__(256, 3)
void attn_kernel(const __bf16* __restrict__ Qb, const __bf16* __restrict__ Kb,
                 const __bf16* __restrict__ Vb, __bf16* __restrict__ Ao)
{
    __shared__ __bf16 Ob[3][64*68];   // bf16 partial O^T, stride 68
    __shared__ float  Lb[4][64];
    const int tid  = threadIdx.x;
    const int lane = tid & 63;
    const int wave = tid >> 6;
    const int quad = lane >> 4;
    const int l16  = lane & 15;
    const int bh    = blockIdx.x;         // 0..15
    const int qBase = blockIdx.y * 64;

    const __bf16* qg = Qb + (size_t)bh*256*2*512;
    const __bf16* kg = Kb + (size_t)bh*256*2*512;
    const __bf16* vg = Vb + (size_t)bh*128*4*512;

    // Q as B-operand from blocked layout: one b128 per (t,hb)
    bf16x8 qf[4][2];
    for (int t = 0; t < 4; t++)
        for (int hb = 0; hb < 2; hb++)
            qf[t][hb] = *(const bf16x8*)(qg
                + ((size_t)((qBase >> 4) + t)*2 + hb)*512 + lane*8);

    floatx4 zero = {0.f, 0.f, 0.f, 0.f};
    floatx4 oacc[4][4];   // [t][od]: O^T tile, row d=od*16+quad*4+r, col q=t*16+l16
    for (int t = 0; t < 4; t++)
        for (int od = 0; od < 4; od++) oacc[t][od] = zero;
    float Lacc[4] = {0.f, 0.f, 0.f, 0.f};

    const int key_begin = wave * 1024;
    const __bf16* kptr = kg + (size_t)(key_begin >> 4)*1024 + lane*8;
    const __bf16* vptr = vg + (size_t)(key_begin >> 5)*2048 + lane*8;

    for (int c = 0; c < 32; ++c) {
        bf16x8 kb00 = *(const bf16x8*)(kptr);
        bf16x8 kb01 = *(const bf16x8*)(kptr + 512);
        bf16x8 kb10 = *(const bf16x8*)(kptr + 1024);
        bf16x8 kb11 = *(const bf16x8*)(kptr + 1536);
        bf16x8 vb0  = *(const bf16x8*)(vptr);
        bf16x8 vb1  = *(const bf16x8*)(vptr + 512);
        bf16x8 vb2  = *(const bf16x8*)(vptr + 1024);
        bf16x8 vb3  = *(const bf16x8*)(vptr + 1536);
        kptr += 2048;
        vptr += 2048;

        for (int t = 0; t < 4; t++) {
            // S^T tiles: rows = keys (kt*16 + quad*4+r), cols = queries
            floatx4 z0 = zero, z1 = zero;
            z0 = MFMA16(kb00, qf[t][0], z0);
            z0 = MFMA16(kb01, qf[t][1], z0);
            z1 = MFMA16(kb10, qf[t][0], z1);
            z1 = MFMA16(kb11, qf[t][1], z1);
            float e0[4], e1[4];
            for (int r = 0; r < 4; r++) { e0[r] = EXP2(z0[r]); e1[r] = EXP2(z1[r]); }
            Lacc[t] += (e0[0]+e0[1]+e0[2]+e0[3]) + (e1[0]+e1[1]+e1[2]+e1[3]);
            // P^T B-operand: slots 0..3 = kt0 rows, 4..7 = kt1 rows (pi)
            uintx4 w;
            w[0] = __builtin_bit_cast(uint32, pk2(e0[0], e0[1]));
            w[1] = __builtin_bit_cast(uint32, pk2(e0[2], e0[3]));
            w[2] = __builtin_bit_cast(uint32, pk2(e1[0], e1[1]));
            w[3] = __builtin_bit_cast(uint32, pk2(e1[2], e1[3]));
            bf16x8 pb = __builtin_bit_cast(bf16x8, w);
            oacc[t][0] = MFMA16(vb0, pb, oacc[t][0]);
            oacc[t][1] = MFMA16(vb1, pb, oacc[t][1]);
            oacc[t][2] = MFMA16(vb2, pb, oacc[t][2]);
            oacc[t][3] = MFMA16(vb3, pb, oacc[t][3]);
        }
    }

    // L: sum across quads (rows of S^T live on different quads, same l16=q)
    for (int t = 0; t < 4; t++) {
        float l = Lacc[t];
        l += __shfl_xor(l, 16);
        l += __shfl_xor(l, 32);
        Lacc[t] = l;
    }
    if (lane < 16)
        for (int t = 0; t < 4; t++) Lb[wave][t*16 + lane] = Lacc[t];
    __syncthreads();
    float inv[4];
    for (int t = 0; t < 4; t++) {
        const int q = t*16 + l16;
        inv[t] = 1.0f / (Lb[0][q] + Lb[1][q] + Lb[2][q] + Lb[3][q]);
    }
    if (wave != 0) {
        for (int t = 0; t < 4; t++)
            for (int od = 0; od < 4; od++) {
                bf16x4 v;
                for (int r = 0; r < 4; r++) v[r] = f2bf(oacc[t][od][r] * inv[t]);
                *(bf16x4*)&Ob[wave-1][(t*16 + l16)*68 + od*16 + quad*4] = v;
            }
    }
    __syncthreads();
    if (wave == 0) {
        const int b = bh >> 3, h = bh & 7;
        for (int t = 0; t < 4; t++) {
            const int s = qBase + t*16 + l16;
            for (int od = 0; od < 4; od++) {
                bf16x4 o0 = *(const bf16x4*)&Ob[0][(t*16 + l16)*68 + od*16 + quad*4];
                bf16x4 o1 = *(const bf16x4*)&Ob[1][(t*16 + l16)*68 + od*16 + quad*4];
                bf16x4 o2 = *(const bf16x4*)&Ob[2][(t*16 + l16)*68 + od*16 + quad*4];
                bf16x4 v;
                for (int r = 0; r < 4; r++) {
                    float o = oacc[t][od][r] * inv[t] +
                              (float)o0[r] + (float)o1[r] + (float)o2[r];
                    v[r] = f2bf(o);
                }
                *(bf16x4*)&Ao[((size_t)(b*SEQ + s))*DIM + h*HD + od*16 + quad*4] = v;
            }
        }
    }
}

// ---------------------------------------------------------------------------
// Stage 3: out = attn_out @ w_proj^T + b_proj  (bf16 A, fp32 W in, fp32 out)
// ---------------------------------------------------------------------------
__global__ __launch_bounds__(256)
void gemm_proj(const __bf16* __restrict__ A, const float* __restrict__ W,
               const float* __restrict__ bias, float* __restrict__ Out)
{
    __shared__ __bf16 As[128*32];
    __shared__ __bf16 Bs[128*32];
    const int tid  = threadIdx.x;
    const int lane = tid & 63;
    const int wave = tid >> 6;
    const int quad = lane >> 4;
    const int l16  = lane & 15;
    const int waveM = wave >> 1, waveN = wave & 1;
    const int mBase = blockIdx.y * 128;
    const int nBase = blockIdx.x * 128;

    floatx4 zero = {0.f, 0.f, 0.f, 0.f};
    floatx4 acc[4][4];
    for (int i = 0; i < 4; i++)
        for (int j = 0; j < 4; j++) acc[i][j] = zero;

    const int srow = tid >> 2;
    const int scol = (tid & 3) * 8;

    for (int k0 = 0; k0 < DIM; k0 += 32) {
        bf16x8 a0 = *(const bf16x8*)(A + (size_t)(mBase + srow)      * DIM + k0 + scol);
        bf16x8 a1 = *(const bf16x8*)(A + (size_t)(mBase + 64 + srow) * DIM + k0 + scol);
        const float* wr0 = W + (size_t)(nBase + srow)      * DIM + k0 + scol;
        const float* wr1 = W + (size_t)(nBase + 64 + srow) * DIM + k0 + scol;
        bf16x8 b0 = cvt8(*(const floatx4*)wr0, *(const floatx4*)(wr0 + 4));
        bf16x8 b1 = cvt8(*(const floatx4*)wr1, *(const floatx4*)(wr1 + 4));
        *(bf16x8*)&As[srow*32 + scol]      = a0;
        *(bf16x8*)&As[(64+srow)*32 + scol] = a1;
        *(bf16x8*)&Bs[srow*32 + scol]      = b0;
        *(bf16x8*)&Bs[(64+srow)*32 + scol] = b1;
        __syncthreads();
        bf16x8 af[4], bfr[4];
        for (int mi = 0; mi < 4; mi++)
            af[mi]  = *(const bf16x8*)&As[(waveM*64 + mi*16 + l16)*32 + quad*8];
        for (int ni = 0; ni < 4; ni++)
            bfr[ni] = *(const bf16x8*)&Bs[(waveN*64 + ni*16 + l16)*32 + quad*8];
        for (int mi = 0; mi < 4; mi++)
            for (int ni = 0; ni < 4; ni++)
                acc[mi][ni] = MFMA16(af[mi], bfr[ni], acc[mi][ni]);
        __syncthreads();
    }

    for (int ni = 0; ni < 4; ni++) {
        const int n = nBase + waveN*64 + ni*16 + l16;
        const float bv = bias[n];
        for (int mi = 0; mi < 4; mi++) {
            const int m0 = mBase + waveM*64 + mi*16 + quad*4;
            for (int r = 0; r < 4; r++) {
                const int mm = m0 + r;
                Out[(size_t)mm*DIM + n] = acc[mi][ni][r] + bv;
            }
        }
    }
}

extern "C" void kernel_launch(void* const* d_in, const int* in_sizes, int n_in,
                              void* d_out, int out_size, void* d_ws, size_t ws_size,
                              hipStream_t stream) {
    const float* x      = (const float*)d_in[0];   // [2,4096,512] fp32
    const float* w_qkv  = (const float*)d_in[1];   // [1536,512] fp32
    const float* b_qkv  = (const float*)d_in[2];   // [1536] fp32
    const float* w_proj = (const float*)d_in[3];   // [512,512] fp32
    const float* b_proj = (const float*)d_in[4];   // [512] fp32
    float* out = (float*)d_out;                    // [2,4096,512] fp32

    __bf16* ws  = (__bf16*)d_ws;
    const size_t PLANE = (size_t)16 * SEQ * HD;    // 4 Mi elements = 8 MB
    __bf16* Qbk = ws;                 // Qblk [16][256][2][64][8] (pre-scaled)
    __bf16* Kbk = ws + PLANE;         // Kblk [16][256][2][64][8]
    __bf16* Vbk = ws + 2*PLANE;       // Vblk [16][128][4][64][8]
    __bf16* Aob = ws + 3*PLANE;       // [2,4096,512] attention output (bf16)

    gemm_qkv<<<dim3(12, 64), 256, 0, stream>>>(x, w_qkv, b_qkv, Qbk, Kbk, Vbk);
    attn_kernel<<<dim3(16, 64), 256, 0, stream>>>(Qbk, Kbk, Vbk, Aob);
    gemm_proj<<<dim3(4, 64), 256, 0, stream>>>(Aob, w_proj, b_proj, out);
}

// Round 8
// 230.603 us; speedup vs baseline: 1.5780x; 1.0064x over previous
//
#include <hip/hip_runtime.h>

typedef __bf16 bf16x8 __attribute__((ext_vector_type(8)));
typedef __bf16 bf16x4 __attribute__((ext_vector_type(4)));
typedef __bf16 bf16x2 __attribute__((ext_vector_type(2)));
typedef float  floatx4 __attribute__((ext_vector_type(4)));
typedef unsigned int uint32;
typedef uint32 uintx4 __attribute__((ext_vector_type(4)));

#define MFMA16(a,b,c) __builtin_amdgcn_mfma_f32_16x16x32_bf16(a,b,c,0,0,0)

constexpr int DIM  = 512;
constexpr int SEQ  = 4096;
constexpr int HD   = 64;
// 0.125 (HEAD_DIM^-0.5) * log2(e), folded into Q so softmax uses exp2 directly
constexpr float QSCALE = 0.1803368801111244f;

static __device__ inline __bf16 f2bf(float f) {
    unsigned int u = __builtin_bit_cast(unsigned int, f);
    u += 0x7fffu + ((u >> 16) & 1u);
    return __builtin_bit_cast(__bf16, (unsigned short)(u >> 16));
}
#if __has_builtin(__builtin_amdgcn_cvt_pk_bf16_f32)
static __device__ inline bf16x2 pk2(float a, float b) {
    return __builtin_amdgcn_cvt_pk_bf16_f32(a, b);
}
#else
static __device__ inline bf16x2 pk2(float a, float b) {
    bf16x2 r; r[0] = f2bf(a); r[1] = f2bf(b); return r;
}
#endif
#if __has_builtin(__builtin_amdgcn_exp2f)
#define EXP2(x) __builtin_amdgcn_exp2f(x)
#else
#define EXP2(x) exp2f(x)
#endif
static __device__ inline bf16x8 cvt8(floatx4 lo, floatx4 hi) {
    uintx4 w;
    w[0] = __builtin_bit_cast(uint32, pk2(lo[0], lo[1]));
    w[1] = __builtin_bit_cast(uint32, pk2(lo[2], lo[3]));
    w[2] = __builtin_bit_cast(uint32, pk2(hi[0], hi[1]));
    w[3] = __builtin_bit_cast(uint32, pk2(hi[2], hi[3]));
    return __builtin_bit_cast(bf16x8, w);
}

// async global->LDS, 16B per lane; LDS dest = wave-uniform base + lane*16B
static __device__ inline void gload16(const __bf16* g, __bf16* l) {
#if __has_builtin(__builtin_amdgcn_global_load_lds)
    __builtin_amdgcn_global_load_lds(
        (const __attribute__((address_space(1))) unsigned int*)g,
        (__attribute__((address_space(3))) unsigned int*)l, 16, 0, 0);
#else
    *(bf16x8*)(l + (threadIdx.x & 63)*8) = *(const bf16x8*)g;
#endif
}

// ---------------------------------------------------------------------------
// Stage 0: convert X fp32 -> bf16 once (removes per-tile re-conversion).
// ---------------------------------------------------------------------------
constexpr int NX = 2*SEQ*DIM;   // 4,194,304
__global__ __launch_bounds__(256)
void cvt_x(const float* __restrict__ X, __bf16* __restrict__ Xb)
{
    const int i = (blockIdx.x*256 + threadIdx.x) * 8;
    floatx4 lo = *(const floatx4*)(X + i);
    floatx4 hi = *(const floatx4*)(X + i + 4);
    *(bf16x8*)(Xb + i) = cvt8(lo, hi);
}

// Blocked fragment layout for Q and K (A/B-operand ready, b128 loads):
//   blk[bh][s>>4][d>>5][lane][8], lane = ((d>>3)&3)*16 + (s&15), slot = d&7
// V blocked under key-permutation pi(q,j)=16*(j>=4)+4q+(j&3):
//   Vblk[bh][s>>5][d>>4][lane][8], lane = ((s>>2)&3)*16 + (d&15),
//   slot j = (s&3) + ((s>>4)&1)*4.

// ---------------------------------------------------------------------------
// Stage 1: qkv = xb @ w_qkv^T + b_qkv (bf16 A via global_load_lds staging,
// fp32 W converted inline, bf16 MFMA, blocked bf16 out).
// Grid (64 m-tiles, 12 n-tiles): XCD = blockIdx.x%8 -> all n-tiles of an
// m-tile share the A rows in one L2.
// ---------------------------------------------------------------------------
__global__ __launch_bounds__(256)
void gemm_qkv(const __bf16* __restrict__ X, const float* __restrict__ W,
              const float* __restrict__ bias,
              __bf16* __restrict__ Qb, __bf16* __restrict__ Kb, __bf16* __restrict__ Vb)
{
    __shared__ __bf16 As[128*32];
    __shared__ __bf16 Bs[128*32];
    const int tid  = threadIdx.x;
    const int lane = tid & 63;
    const int wave = tid >> 6;
    const int quad = lane >> 4;
    const int l16  = lane & 15;
    const int waveM = wave >> 1, waveN = wave & 1;
    const int mBase = blockIdx.x * 128;
    const int nBase = blockIdx.y * 128;
    const int which = nBase >> 9;          // 0=q 1=k 2=v (uniform per block)

    floatx4 zero = {0.f, 0.f, 0.f, 0.f};
    floatx4 acc[4][4];
    for (int i = 0; i < 4; i++)
        for (int j = 0; j < 4; j++) acc[i][j] = zero;

    const int srow = tid >> 2;        // 0..63
    const int scol = (tid & 3) * 8;   // 0,8,16,24
    // A staging via global_load_lds: wave covers rows 32w..32w+32 (2 instrs)
    const __bf16* gA0 = X + (size_t)(mBase + 32*wave + (lane >> 2))*DIM + (lane & 3)*8;
    __bf16* lA0 = &As[(32*wave)*32];
    __bf16* lA1 = &As[(32*wave + 16)*32];

    for (int k0 = 0; k0 < DIM; k0 += 32) {
        gload16(gA0 + k0,             lA0);
        gload16(gA0 + k0 + 16*DIM,    lA1);
        const float* wr0 = W + (size_t)(nBase + srow)      * DIM + k0 + scol;
        const float* wr1 = W + (size_t)(nBase + 64 + srow) * DIM + k0 + scol;
        bf16x8 b0 = cvt8(*(const floatx4*)wr0, *(const floatx4*)(wr0 + 4));
        bf16x8 b1 = cvt8(*(const floatx4*)wr1, *(const floatx4*)(wr1 + 4));
        *(bf16x8*)&Bs[srow*32 + scol]      = b0;
        *(bf16x8*)&Bs[(64+srow)*32 + scol] = b1;
        __syncthreads();
        bf16x8 af[4], bfr[4];
        for (int mi = 0; mi < 4; mi++)
            af[mi]  = *(const bf16x8*)&As[(waveM*64 + mi*16 + l16)*32 + quad*8];
        for (int ni = 0; ni < 4; ni++)
            bfr[ni] = *(const bf16x8*)&Bs[(waveN*64 + ni*16 + l16)*32 + quad*8];
        if (which == 2) {
            for (int mi = 0; mi < 4; mi++)
                for (int ni = 0; ni < 4; ni++)
                    acc[mi][ni] = MFMA16(af[mi], bfr[ni], acc[mi][ni]);
        } else {
            // transposed: rows = W-rows (d), cols = X-rows (s)
            for (int mi = 0; mi < 4; mi++)
                for (int ni = 0; ni < 4; ni++)
                    acc[mi][ni] = MFMA16(bfr[ni], af[mi], acc[mi][ni]);
        }
        __syncthreads();
    }

    if (which == 2) {
        // V epilogue (normal orientation): rows = s, cols = n/d
        for (int ni = 0; ni < 4; ni++) {
            const int n = nBase + waveN*64 + ni*16 + l16;
            const float bv = bias[n];
            const int h = (n >> 6) & 7;
            const int d = n & 63;
            for (int mi = 0; mi < 4; mi++) {
                const int m0 = mBase + waveM*64 + mi*16 + quad*4;
                const int b  = m0 >> 12;
                const int s0 = m0 & 4095;
                const int bh = (b << 3) | h;
                bf16x4 v;
                for (int r = 0; r < 4; r++) v[r] = f2bf(acc[mi][ni][r] + bv);
                size_t off = (((((size_t)bh*128 + (s0 >> 5))*4 + (d >> 4))*64)
                              + ((s0 >> 2) & 3)*16 + (d & 15))*8 + ((s0 >> 4) & 1)*4;
                *(bf16x4*)&Vb[off] = v;
            }
        }
    } else {
        // Q/K epilogue (transposed): rows = d (quad*4+r), cols = s (l16)
        __bf16* dst = (which == 0) ? Qb : Kb;
        for (int ni = 0; ni < 4; ni++) {
            const int n0 = nBase + waveN*64 + ni*16 + quad*4;
            const floatx4 b4 = *(const floatx4*)&bias[n0];
            const int dfull = n0 & 511;           // 0..511 within q or k section
            const int h  = dfull >> 6;
            const int d0 = dfull & 63;            // 4-aligned
            const int lgrp = ((d0 >> 3) & 3)*16 + l16;
            const int half = d0 >> 5;
            const int slot = d0 & 7;              // 0 or 4
            for (int mi = 0; mi < 4; mi++) {
                const int m = mBase + waveM*64 + mi*16 + l16;
                const int b = m >> 12, s = m & 4095;
                const int bh = (b << 3) | h;
                bf16x4 v;
                for (int r = 0; r < 4; r++) {
                    float val = acc[mi][ni][r] + b4[r];
                    if (which == 0) val *= QSCALE;
                    v[r] = f2bf(val);
                }
                size_t off = ((((size_t)bh*256 + (s >> 4))*2 + half)*64 + lgrp)*8 + slot;
                *(bf16x4*)&dst[off] = v;
            }
        }
    }
}

// ---------------------------------------------------------------------------
// Stage 2: flash attention — R7 verified core, untouched.
// ---------------------------------------------------------------------------
__global__ __launch_bounds__(256, 3)
void attn_kernel(const __bf16* __restrict__ Qb, const __bf16* __restrict__ Kb,
                 const __bf16* __restrict__ Vb, __bf16* __restrict__ Ao)
{
    __shared__ __bf16 Ob[3][64*68];   // bf16 partial O^T, stride 68
    __shared__ float  Lb[4][64];
    const int tid  = threadIdx.x;
    const int lane = tid & 63;
    const int wave = tid >> 6;
    const int quad = lane >> 4;
    const int l16  = lane & 15;
    const int bh    = blockIdx.x;         // 0..15
    const int qBase = blockIdx.y * 64;

    const __bf16* qg = Qb + (size_t)bh*256*2*512;
    const __bf16* kg = Kb + (size_t)bh*256*2*512;
    const __bf16* vg = Vb + (size_t)bh*128*4*512;

    bf16x8 qf[4][2];
    for (int t = 0; t < 4; t++)
        for (int hb = 0; hb < 2; hb++)
            qf[t][hb] = *(const bf16x8*)(qg
                + ((size_t)((qBase >> 4) + t)*2 + hb)*512 + lane*8);

    floatx4 zero = {0.f, 0.f, 0.f, 0.f};
    floatx4 oacc[4][4];   // [t][od]: O^T tile, row d=od*16+quad*4+r, col q=t*16+l16
    for (int t = 0; t < 4; t++)
        for (int od = 0; od < 4; od++) oacc[t][od] = zero;
    float Lacc[4] = {0.f, 0.f, 0.f, 0.f};

    const int key_begin = wave * 1024;
    const __bf16* kptr = kg + (size_t)(key_begin >> 4)*1024 + lane*8;
    const __bf16* vptr = vg + (size_t)(key_begin >> 5)*2048 + lane*8;

    for (int c = 0; c < 32; ++c) {
        bf16x8 kb00 = *(const bf16x8*)(kptr);
        bf16x8 kb01 = *(const bf16x8*)(kptr + 512);
        bf16x8 kb10 = *(const bf16x8*)(kptr + 1024);
        bf16x8 kb11 = *(const bf16x8*)(kptr + 1536);
        bf16x8 vb0  = *(const bf16x8*)(vptr);
        bf16x8 vb1  = *(const bf16x8*)(vptr + 512);
        bf16x8 vb2  = *(const bf16x8*)(vptr + 1024);
        bf16x8 vb3  = *(const bf16x8*)(vptr + 1536);
        kptr += 2048;
        vptr += 2048;

        for (int t = 0; t < 4; t++) {
            floatx4 z0 = zero, z1 = zero;
            z0 = MFMA16(kb00, qf[t][0], z0);
            z0 = MFMA16(kb01, qf[t][1], z0);
            z1 = MFMA16(kb10, qf[t][0], z1);
            z1 = MFMA16(kb11, qf[t][1], z1);
            float e0[4], e1[4];
            for (int r = 0; r < 4; r++) { e0[r] = EXP2(z0[r]); e1[r] = EXP2(z1[r]); }
            Lacc[t] += (e0[0]+e0[1]+e0[2]+e0[3]) + (e1[0]+e1[1]+e1[2]+e1[3]);
            uintx4 w;
            w[0] = __builtin_bit_cast(uint32, pk2(e0[0], e0[1]));
            w[1] = __builtin_bit_cast(uint32, pk2(e0[2], e0[3]));
            w[2] = __builtin_bit_cast(uint32, pk2(e1[0], e1[1]));
            w[3] = __builtin_bit_cast(uint32, pk2(e1[2], e1[3]));
            bf16x8 pb = __builtin_bit_cast(bf16x8, w);
            oacc[t][0] = MFMA16(vb0, pb, oacc[t][0]);
            oacc[t][1] = MFMA16(vb1, pb, oacc[t][1]);
            oacc[t][2] = MFMA16(vb2, pb, oacc[t][2]);
            oacc[t][3] = MFMA16(vb3, pb, oacc[t][3]);
        }
    }

    for (int t = 0; t < 4; t++) {
        float l = Lacc[t];
        l += __shfl_xor(l, 16);
        l += __shfl_xor(l, 32);
        Lacc[t] = l;
    }
    if (lane < 16)
        for (int t = 0; t < 4; t++) Lb[wave][t*16 + lane] = Lacc[t];
    __syncthreads();
    float inv[4];
    for (int t = 0; t < 4; t++) {
        const int q = t*16 + l16;
        inv[t] = 1.0f / (Lb[0][q] + Lb[1][q] + Lb[2][q] + Lb[3][q]);
    }
    if (wave != 0) {
        for (int t = 0; t < 4; t++)
            for (int od = 0; od < 4; od++) {
                bf16x4 v;
                for (int r = 0; r < 4; r++) v[r] = f2bf(oacc[t][od][r] * inv[t]);
                *(bf16x4*)&Ob[wave-1][(t*16 + l16)*68 + od*16 + quad*4] = v;
            }
    }
    __syncthreads();
    if (wave == 0) {
        const int b = bh >> 3, h = bh & 7;
        for (int t = 0; t < 4; t++) {
            const int s = qBase + t*16 + l16;
            for (int od = 0; od < 4; od++) {
                bf16x4 o0 = *(const bf16x4*)&Ob[0][(t*16 + l16)*68 + od*16 + quad*4];
                bf16x4 o1 = *(const bf16x4*)&Ob[1][(t*16 + l16)*68 + od*16 + quad*4];
                bf16x4 o2 = *(const bf16x4*)&Ob[2][(t*16 + l16)*68 + od*16 + quad*4];
                bf16x4 v;
                for (int r = 0; r < 4; r++) {
                    float o = oacc[t][od][r] * inv[t] +
                              (float)o0[r] + (float)o1[r] + (float)o2[r];
                    v[r] = f2bf(o);
                }
                *(bf16x4*)&Ao[((size_t)(b*SEQ + s))*DIM + h*HD + od*16 + quad*4] = v;
            }
        }
    }
}

// ---------------------------------------------------------------------------
// Stage 3: out = attn_out @ w_proj^T + b_proj  (bf16 A via global_load_lds,
// fp32 W inline-cvt, fp32 out). Grid (64 m-tiles, 4 n-tiles).
// ---------------------------------------------------------------------------
__global__ __launch_bounds__(256)
void gemm_proj(const __bf16* __restrict__ A, const float* __restrict__ W,
               const float* __restrict__ bias, float* __restrict__ Out)
{
    __shared__ __bf16 As[128*32];
    __shared__ __bf16 Bs[128*32];
    const int tid  = threadIdx.x;
    const int lane = tid & 63;
    const int wave = tid >> 6;
    const int quad = lane >> 4;
    const int l16  = lane & 15;
    const int waveM = wave >> 1, waveN = wave & 1;
    const int mBase = blockIdx.x * 128;
    const int nBase = blockIdx.y * 128;

    floatx4 zero = {0.f, 0.f, 0.f, 0.f};
    floatx4 acc[4][4];
    for (int i = 0; i < 4; i++)
        for (int j = 0; j < 4; j++) acc[i][j] = zero;

    const int srow = tid >> 2;
    const int scol = (tid & 3) * 8;
    const __bf16* gA0 = A + (size_t)(mBase + 32*wave + (lane >> 2))*DIM + (lane & 3)*8;
    __bf16* lA0 = &As[(32*wave)*32];
    __bf16* lA1 = &As[(32*wave + 16)*32];

    for (int k0 = 0; k0 < DIM; k0 += 32) {
        gload16(gA0 + k0,          lA0);
        gload16(gA0 + k0 + 16*DIM, lA1);
        const float* wr0 = W + (size_t)(nBase + srow)      * DIM + k0 + scol;
        const float* wr1 = W + (size_t)(nBase + 64 + srow) * DIM + k0 + scol;
        bf16x8 b0 = cvt8(*(const floatx4*)wr0, *(const floatx4*)(wr0 + 4));
        bf16x8 b1 = cvt8(*(const floatx4*)wr1, *(const floatx4*)(wr1 + 4));
        *(bf16x8*)&Bs[srow*32 + scol]      = b0;
        *(bf16x8*)&Bs[(64+srow)*32 + scol] = b1;
        __syncthreads();
        bf16x8 af[4], bfr[4];
        for (int mi = 0; mi < 4; mi++)
            af[mi]  = *(const bf16x8*)&As[(waveM*64 + mi*16 + l16)*32 + quad*8];
        for (int ni = 0; ni < 4; ni++)
            bfr[ni] = *(const bf16x8*)&Bs[(waveN*64 + ni*16 + l16)*32 + quad*8];
        for (int mi = 0; mi < 4; mi++)
            for (int ni = 0; ni < 4; ni++)
                acc[mi][ni] = MFMA16(af[mi], bfr[ni], acc[mi][ni]);
        __syncthreads();
    }

    for (int ni = 0; ni < 4; ni++) {
        const int n = nBase + waveN*64 + ni*16 + l16;
        const float bv = bias[n];
        for (int mi = 0; mi < 4; mi++) {
            const int m0 = mBase + waveM*64 + mi*16 + quad*4;
            for (int r = 0; r < 4; r++) {
                const int mm = m0 + r;
                Out[(size_t)mm*DIM + n] = acc[mi][ni][r] + bv;
            }
        }
    }
}

extern "C" void kernel_launch(void* const* d_in, const int* in_sizes, int n_in,
                              void* d_out, int out_size, void* d_ws, size_t ws_size,
                              hipStream_t stream) {
    const float* x      = (const float*)d_in[0];   // [2,4096,512] fp32
    const float* w_qkv  = (const float*)d_in[1];   // [1536,512] fp32
    const float* b_qkv  = (const float*)d_in[2];   // [1536] fp32
    const float* w_proj = (const float*)d_in[3];   // [512,512] fp32
    const float* b_proj = (const float*)d_in[4];   // [512] fp32
    float* out = (float*)d_out;                    // [2,4096,512] fp32

    __bf16* ws  = (__bf16*)d_ws;
    const size_t PLANE = (size_t)16 * SEQ * HD;    // 4 Mi elements = 8 MB
    __bf16* Qbk = ws;                 // Qblk [16][256][2][64][8] (pre-scaled)
    __bf16* Kbk = ws + PLANE;         // Kblk [16][256][2][64][8]
    __bf16* Vbk = ws + 2*PLANE;       // Vblk [16][128][4][64][8]
    __bf16* R0  = ws + 3*PLANE;       // shared: Xb (prepass->qkv), then Aob (attn->proj)
    __bf16* Xb  = R0;
    __bf16* Aob = R0;

    cvt_x<<<dim3(NX/(256*8)), 256, 0, stream>>>(x, Xb);
    gemm_qkv<<<dim3(64, 12), 256, 0, stream>>>(Xb, w_qkv, b_qkv, Qbk, Kbk, Vbk);
    attn_kernel<<<dim3(16, 64), 256, 0, stream>>>(Qbk, Kbk, Vbk, Aob);
    gemm_proj<<<dim3(64, 4), 256, 0, stream>>>(Aob, w_proj, b_proj, out);
}

// Round 9
// 223.352 us; speedup vs baseline: 1.6292x; 1.0325x over previous
//
#include <hip/hip_runtime.h>

typedef __bf16 bf16x8 __attribute__((ext_vector_type(8)));
typedef __bf16 bf16x4 __attribute__((ext_vector_type(4)));
typedef __bf16 bf16x2 __attribute__((ext_vector_type(2)));
typedef float  floatx4 __attribute__((ext_vector_type(4)));
typedef unsigned int uint32;
typedef uint32 uintx4 __attribute__((ext_vector_type(4)));

#define MFMA16(a,b,c) __builtin_amdgcn_mfma_f32_16x16x32_bf16(a,b,c,0,0,0)

constexpr int DIM  = 512;
constexpr int SEQ  = 4096;
constexpr int HD   = 64;
// 0.125 (HEAD_DIM^-0.5) * log2(e), folded into Q so softmax uses exp2 directly
constexpr float QSCALE = 0.1803368801111244f;

static __device__ inline __bf16 f2bf(float f) {
    unsigned int u = __builtin_bit_cast(unsigned int, f);
    u += 0x7fffu + ((u >> 16) & 1u);
    return __builtin_bit_cast(__bf16, (unsigned short)(u >> 16));
}
#if __has_builtin(__builtin_amdgcn_cvt_pk_bf16_f32)
static __device__ inline bf16x2 pk2(float a, float b) {
    return __builtin_amdgcn_cvt_pk_bf16_f32(a, b);
}
#else
static __device__ inline bf16x2 pk2(float a, float b) {
    bf16x2 r; r[0] = f2bf(a); r[1] = f2bf(b); return r;
}
#endif
#if __has_builtin(__builtin_amdgcn_exp2f)
#define EXP2(x) __builtin_amdgcn_exp2f(x)
#else
#define EXP2(x) exp2f(x)
#endif
static __device__ inline bf16x8 cvt8(floatx4 lo, floatx4 hi) {
    uintx4 w;
    w[0] = __builtin_bit_cast(uint32, pk2(lo[0], lo[1]));
    w[1] = __builtin_bit_cast(uint32, pk2(lo[2], lo[3]));
    w[2] = __builtin_bit_cast(uint32, pk2(hi[0], hi[1]));
    w[3] = __builtin_bit_cast(uint32, pk2(hi[2], hi[3]));
    return __builtin_bit_cast(bf16x8, w);
}

// async global->LDS, 16B per lane; LDS dest = wave-uniform base + lane*16B
static __device__ inline void gload16(const __bf16* g, __bf16* l) {
#if __has_builtin(__builtin_amdgcn_global_load_lds)
    __builtin_amdgcn_global_load_lds(
        (const __attribute__((address_space(1))) unsigned int*)g,
        (__attribute__((address_space(3))) unsigned int*)l, 16, 0, 0);
#else
    *(bf16x8*)(l + (threadIdx.x & 63)*8) = *(const bf16x8*)g;
#endif
}

// Blocked fragment layout for Q and K (A/B-operand ready, b128 loads):
//   blk[bh][s>>4][d>>5][lane][8], lane = ((d>>3)&3)*16 + (s&15), slot = d&7
// V blocked under key-permutation pi(q,j)=16*(j>=4)+4q+(j&3):
//   Vblk[bh][s>>5][d>>4][lane][8], lane = ((s>>2)&3)*16 + (d&15),
//   slot j = (s&3) + ((s>>4)&1)*4.

// ---------------------------------------------------------------------------
// Stage 1: qkv = x @ w_qkv^T + b_qkv (fp32 in, inline cvt, bf16 MFMA,
// blocked bf16 out). Grid (64 m-tiles, 12 n-tiles): all n-tiles of an
// m-tile land on XCD x%8 (linear%8), sharing the X rows in one L2.
// ---------------------------------------------------------------------------
__global__ __launch_bounds__(256)
void gemm_qkv(const float* __restrict__ X, const float* __restrict__ W,
              const float* __restrict__ bias,
              __bf16* __restrict__ Qb, __bf16* __restrict__ Kb, __bf16* __restrict__ Vb)
{
    __shared__ __bf16 As[128*32];
    __shared__ __bf16 Bs[128*32];
    const int tid  = threadIdx.x;
    const int lane = tid & 63;
    const int wave = tid >> 6;
    const int quad = lane >> 4;
    const int l16  = lane & 15;
    const int waveM = wave >> 1, waveN = wave & 1;
    const int mBase = blockIdx.x * 128;
    const int nBase = blockIdx.y * 128;
    const int which = nBase >> 9;          // 0=q 1=k 2=v (uniform per block)

    floatx4 zero = {0.f, 0.f, 0.f, 0.f};
    floatx4 acc[4][4];
    for (int i = 0; i < 4; i++)
        for (int j = 0; j < 4; j++) acc[i][j] = zero;

    const int srow = tid >> 2;        // 0..63
    const int scol = (tid & 3) * 8;   // 0,8,16,24

    for (int k0 = 0; k0 < DIM; k0 += 32) {
        const float* xr0 = X + (size_t)(mBase + srow)      * DIM + k0 + scol;
        const float* xr1 = X + (size_t)(mBase + 64 + srow) * DIM + k0 + scol;
        const float* wr0 = W + (size_t)(nBase + srow)      * DIM + k0 + scol;
        const float* wr1 = W + (size_t)(nBase + 64 + srow) * DIM + k0 + scol;
        bf16x8 a0 = cvt8(*(const floatx4*)xr0, *(const floatx4*)(xr0 + 4));
        bf16x8 a1 = cvt8(*(const floatx4*)xr1, *(const floatx4*)(xr1 + 4));
        bf16x8 b0 = cvt8(*(const floatx4*)wr0, *(const floatx4*)(wr0 + 4));
        bf16x8 b1 = cvt8(*(const floatx4*)wr1, *(const floatx4*)(wr1 + 4));
        *(bf16x8*)&As[srow*32 + scol]      = a0;
        *(bf16x8*)&As[(64+srow)*32 + scol] = a1;
        *(bf16x8*)&Bs[srow*32 + scol]      = b0;
        *(bf16x8*)&Bs[(64+srow)*32 + scol] = b1;
        __syncthreads();
        bf16x8 af[4], bfr[4];
        for (int mi = 0; mi < 4; mi++)
            af[mi]  = *(const bf16x8*)&As[(waveM*64 + mi*16 + l16)*32 + quad*8];
        for (int ni = 0; ni < 4; ni++)
            bfr[ni] = *(const bf16x8*)&Bs[(waveN*64 + ni*16 + l16)*32 + quad*8];
        if (which == 2) {
            for (int mi = 0; mi < 4; mi++)
                for (int ni = 0; ni < 4; ni++)
                    acc[mi][ni] = MFMA16(af[mi], bfr[ni], acc[mi][ni]);
        } else {
            // transposed: rows = W-rows (d), cols = X-rows (s)
            for (int mi = 0; mi < 4; mi++)
                for (int ni = 0; ni < 4; ni++)
                    acc[mi][ni] = MFMA16(bfr[ni], af[mi], acc[mi][ni]);
        }
        __syncthreads();
    }

    if (which == 2) {
        // V epilogue (normal orientation): rows = s, cols = n/d
        for (int ni = 0; ni < 4; ni++) {
            const int n = nBase + waveN*64 + ni*16 + l16;
            const float bv = bias[n];
            const int h = (n >> 6) & 7;
            const int d = n & 63;
            for (int mi = 0; mi < 4; mi++) {
                const int m0 = mBase + waveM*64 + mi*16 + quad*4;
                const int b  = m0 >> 12;
                const int s0 = m0 & 4095;
                const int bh = (b << 3) | h;
                bf16x4 v;
                for (int r = 0; r < 4; r++) v[r] = f2bf(acc[mi][ni][r] + bv);
                size_t off = (((((size_t)bh*128 + (s0 >> 5))*4 + (d >> 4))*64)
                              + ((s0 >> 2) & 3)*16 + (d & 15))*8 + ((s0 >> 4) & 1)*4;
                *(bf16x4*)&Vb[off] = v;
            }
        }
    } else {
        // Q/K epilogue (transposed): rows = d (quad*4+r), cols = s (l16)
        __bf16* dst = (which == 0) ? Qb : Kb;
        for (int ni = 0; ni < 4; ni++) {
            const int n0 = nBase + waveN*64 + ni*16 + quad*4;
            const floatx4 b4 = *(const floatx4*)&bias[n0];
            const int dfull = n0 & 511;           // 0..511 within q or k section
            const int h  = dfull >> 6;
            const int d0 = dfull & 63;            // 4-aligned
            const int lgrp = ((d0 >> 3) & 3)*16 + l16;
            const int half = d0 >> 5;
            const int slot = d0 & 7;              // 0 or 4
            for (int mi = 0; mi < 4; mi++) {
                const int m = mBase + waveM*64 + mi*16 + l16;
                const int b = m >> 12, s = m & 4095;
                const int bh = (b << 3) | h;
                bf16x4 v;
                for (int r = 0; r < 4; r++) {
                    float val = acc[mi][ni][r] + b4[r];
                    if (which == 0) val *= QSCALE;
                    v[r] = f2bf(val);
                }
                size_t off = ((((size_t)bh*256 + (s >> 4))*2 + half)*64 + lgrp)*8 + slot;
                *(bf16x4*)&dst[off] = v;
            }
        }
    }
}

// ---------------------------------------------------------------------------
// Stage 2: flash attention — R7 verified core + L via ones-MFMA (replaces
// per-chunk VALU adds and end-shuffles; MFMA pipe has headroom at 31%).
// ---------------------------------------------------------------------------
__global__ __launch_bounds__(256, 3)
void attn_kernel(const __bf16* __restrict__ Qb, const __bf16* __restrict__ Kb,
                 const __bf16* __restrict__ Vb, __bf16* __restrict__ Ao)
{
    __shared__ __bf16 Ob[3][64*68];   // bf16 partial O^T, stride 68
    __shared__ float  Lb[4][64];
    const int tid  = threadIdx.x;
    const int lane = tid & 63;
    const int wave = tid >> 6;
    const int quad = lane >> 4;
    const int l16  = lane & 15;
    const int bh    = blockIdx.x;         // 0..15
    const int qBase = blockIdx.y * 64;

    const __bf16* qg = Qb + (size_t)bh*256*2*512;
    const __bf16* kg = Kb + (size_t)bh*256*2*512;
    const __bf16* vg = Vb + (size_t)bh*128*4*512;

    bf16x8 qf[4][2];
    for (int t = 0; t < 4; t++)
        for (int hb = 0; hb < 2; hb++)
            qf[t][hb] = *(const bf16x8*)(qg
                + ((size_t)((qBase >> 4) + t)*2 + hb)*512 + lane*8);

    floatx4 zero = {0.f, 0.f, 0.f, 0.f};
    floatx4 oacc[4][4];   // [t][od]: O^T tile, row d=od*16+quad*4+r, col q=t*16+l16
    for (int t = 0; t < 4; t++)
        for (int od = 0; od < 4; od++) oacc[t][od] = zero;
    floatx4 Lt[4];        // ones-MFMA: every row of Lt[t] = L[q=t*16+l16]
    for (int t = 0; t < 4; t++) Lt[t] = zero;

    bf16x8 ones;
    for (int j = 0; j < 8; j++) ones[j] = f2bf(1.0f);

    const int key_begin = wave * 1024;
    const __bf16* kptr = kg + (size_t)(key_begin >> 4)*1024 + lane*8;
    const __bf16* vptr = vg + (size_t)(key_begin >> 5)*2048 + lane*8;

    for (int c = 0; c < 32; ++c) {
        bf16x8 kb00 = *(const bf16x8*)(kptr);
        bf16x8 kb01 = *(const bf16x8*)(kptr + 512);
        bf16x8 kb10 = *(const bf16x8*)(kptr + 1024);
        bf16x8 kb11 = *(const bf16x8*)(kptr + 1536);
        bf16x8 vb0  = *(const bf16x8*)(vptr);
        bf16x8 vb1  = *(const bf16x8*)(vptr + 512);
        bf16x8 vb2  = *(const bf16x8*)(vptr + 1024);
        bf16x8 vb3  = *(const bf16x8*)(vptr + 1536);
        kptr += 2048;
        vptr += 2048;

        for (int t = 0; t < 4; t++) {
            floatx4 z0 = zero, z1 = zero;
            z0 = MFMA16(kb00, qf[t][0], z0);
            z0 = MFMA16(kb01, qf[t][1], z0);
            z1 = MFMA16(kb10, qf[t][0], z1);
            z1 = MFMA16(kb11, qf[t][1], z1);
            float e0[4], e1[4];
            for (int r = 0; r < 4; r++) { e0[r] = EXP2(z0[r]); e1[r] = EXP2(z1[r]); }
            uintx4 w;
            w[0] = __builtin_bit_cast(uint32, pk2(e0[0], e0[1]));
            w[1] = __builtin_bit_cast(uint32, pk2(e0[2], e0[3]));
            w[2] = __builtin_bit_cast(uint32, pk2(e1[0], e1[1]));
            w[3] = __builtin_bit_cast(uint32, pk2(e1[2], e1[3]));
            bf16x8 pb = __builtin_bit_cast(bf16x8, w);
            Lt[t] = MFMA16(ones, pb, Lt[t]);
            oacc[t][0] = MFMA16(vb0, pb, oacc[t][0]);
            oacc[t][1] = MFMA16(vb1, pb, oacc[t][1]);
            oacc[t][2] = MFMA16(vb2, pb, oacc[t][2]);
            oacc[t][3] = MFMA16(vb3, pb, oacc[t][3]);
        }
    }

    // L[q] is replicated across rows of Lt[t]; publish per-wave partials
    if (lane < 16)
        for (int t = 0; t < 4; t++) Lb[wave][t*16 + lane] = Lt[t][0];
    __syncthreads();
    float inv[4];
    for (int t = 0; t < 4; t++) {
        const int q = t*16 + l16;
        inv[t] = 1.0f / (Lb[0][q] + Lb[1][q] + Lb[2][q] + Lb[3][q]);
    }
    if (wave != 0) {
        for (int t = 0; t < 4; t++)
            for (int od = 0; od < 4; od++) {
                bf16x4 v;
                for (int r = 0; r < 4; r++) v[r] = f2bf(oacc[t][od][r] * inv[t]);
                *(bf16x4*)&Ob[wave-1][(t*16 + l16)*68 + od*16 + quad*4] = v;
            }
    }
    __syncthreads();
    if (wave == 0) {
        const int b = bh >> 3, h = bh & 7;
        for (int t = 0; t < 4; t++) {
            const int s = qBase + t*16 + l16;
            for (int od = 0; od < 4; od++) {
                bf16x4 o0 = *(const bf16x4*)&Ob[0][(t*16 + l16)*68 + od*16 + quad*4];
                bf16x4 o1 = *(const bf16x4*)&Ob[1][(t*16 + l16)*68 + od*16 + quad*4];
                bf16x4 o2 = *(const bf16x4*)&Ob[2][(t*16 + l16)*68 + od*16 + quad*4];
                bf16x4 v;
                for (int r = 0; r < 4; r++) {
                    float o = oacc[t][od][r] * inv[t] +
                              (float)o0[r] + (float)o1[r] + (float)o2[r];
                    v[r] = f2bf(o);
                }
                *(bf16x4*)&Ao[((size_t)(b*SEQ + s))*DIM + h*HD + od*16 + quad*4] = v;
            }
        }
    }
}

// ---------------------------------------------------------------------------
// Stage 3: out = attn_out @ w_proj^T + b_proj  (bf16 A via global_load_lds,
// fp32 W inline-cvt, fp32 out). Grid (64 m-tiles, 4 n-tiles).
// ---------------------------------------------------------------------------
__global__ __launch_bounds__(256)
void gemm_proj(const __bf16* __restrict__ A, const float* __restrict__ W,
               const float* __restrict__ bias, float* __restrict__ Out)
{
    __shared__ __bf16 As[128*32];
    __shared__ __bf16 Bs[128*32];
    const int tid  = threadIdx.x;
    const int lane = tid & 63;
    const int wave = tid >> 6;
    const int quad = lane >> 4;
    const int l16  = lane & 15;
    const int waveM = wave >> 1, waveN = wave & 1;
    const int mBase = blockIdx.x * 128;
    const int nBase = blockIdx.y * 128;

    floatx4 zero = {0.f, 0.f, 0.f, 0.f};
    floatx4 acc[4][4];
    for (int i = 0; i < 4; i++)
        for (int j = 0; j < 4; j++) acc[i][j] = zero;

    const int srow = tid >> 2;
    const int scol = (tid & 3) * 8;
    const __bf16* gA0 = A + (size_t)(mBase + 32*wave + (lane >> 2))*DIM + (lane & 3)*8;
    __bf16* lA0 = &As[(32*wave)*32];
    __bf16* lA1 = &As[(32*wave + 16)*32];

    for (int k0 = 0; k0 < DIM; k0 += 32) {
        gload16(gA0 + k0,          lA0);
        gload16(gA0 + k0 + 16*DIM, lA1);
        const float* wr0 = W + (size_t)(nBase + srow)      * DIM + k0 + scol;
        const float* wr1 = W + (size_t)(nBase + 64 + srow) * DIM + k0 + scol;
        bf16x8 b0 = cvt8(*(const floatx4*)wr0, *(const floatx4*)(wr0 + 4));
        bf16x8 b1 = cvt8(*(const floatx4*)wr1, *(const floatx4*)(wr1 + 4));
        *(bf16x8*)&Bs[srow*32 + scol]      = b0;
        *(bf16x8*)&Bs[(64+srow)*32 + scol] = b1;
        __syncthreads();
        bf16x8 af[4], bfr[4];
        for (int mi = 0; mi < 4; mi++)
            af[mi]  = *(const bf16x8*)&As[(waveM*64 + mi*16 + l16)*32 + quad*8];
        for (int ni = 0; ni < 4; ni++)
            bfr[ni] = *(const bf16x8*)&Bs[(waveN*64 + ni*16 + l16)*32 + quad*8];
        for (int mi = 0; mi < 4; mi++)
            for (int ni = 0; ni < 4; ni++)
                acc[mi][ni] = MFMA16(af[mi], bfr[ni], acc[mi][ni]);
        __syncthreads();
    }

    for (int ni = 0; ni < 4; ni++) {
        const int n = nBase + waveN*64 + ni*16 + l16;
        const float bv = bias[n];
        for (int mi = 0; mi < 4; mi++) {
            const int m0 = mBase + waveM*64 + mi*16 + quad*4;
            for (int r = 0; r < 4; r++) {
                const int mm = m0 + r;
                Out[(size_t)mm*DIM + n] = acc[mi][ni][r] + bv;
            }
        }
    }
}

extern "C" void kernel_launch(void* const* d_in, const int* in_sizes, int n_in,
                              void* d_out, int out_size, void* d_ws, size_t ws_size,
                              hipStream_t stream) {
    const float* x      = (const float*)d_in[0];   // [2,4096,512] fp32
    const float* w_qkv  = (const float*)d_in[1];   // [1536,512] fp32
    const float* b_qkv  = (const float*)d_in[2];   // [1536] fp32
    const float* w_proj = (const float*)d_in[3];   // [512,512] fp32
    const float* b_proj = (const float*)d_in[4];   // [512] fp32
    float* out = (float*)d_out;                    // [2,4096,512] fp32

    __bf16* ws  = (__bf16*)d_ws;
    const size_t PLANE = (size_t)16 * SEQ * HD;    // 4 Mi elements = 8 MB
    __bf16* Qbk = ws;                 // Qblk [16][256][2][64][8] (pre-scaled)
    __bf16* Kbk = ws + PLANE;         // Kblk [16][256][2][64][8]
    __bf16* Vbk = ws + 2*PLANE;       // Vblk [16][128][4][64][8]
    __bf16* Aob = ws + 3*PLANE;       // [2,4096,512] attention output (bf16)

    gemm_qkv<<<dim3(64, 12), 256, 0, stream>>>(x, w_qkv, b_qkv, Qbk, Kbk, Vbk);
    attn_kernel<<<dim3(16, 64), 256, 0, stream>>>(Qbk, Kbk, Vbk, Aob);
    gemm_proj<<<dim3(64, 4), 256, 0, stream>>>(Aob, w_proj, b_proj, out);
}